// Round 4
// baseline (188.554 us; speedup 1.0000x reference)
//
#include <hip/hip_runtime.h>

#define NBLOCK 64
#define TPB 256

// sin(x) for |x| <~ 200, abs error ~1e-7.
// Cody-Waite pi/2 reduction (2 fmas) + cephes polys on [-pi/4, pi/4].
__device__ __forceinline__ float fast_sinf(float x) {
    float kf = rintf(x * 0.63661977236758134f);   // round(x * 2/pi)
    int   q  = (int)kf;
    // pi/2 = HI + LO;  HI = float(pi/2), LO = pi/2 - HI = -4.3711390e-8
    float r = fmaf(kf, -1.5707963705062866f, x);  // x - k*HI (fma-exact product)
    r = fmaf(kf, 4.3711390001862171e-8f, r);      // - k*LO
    float z = r * r;
    // sin poly
    float s = fmaf(z, fmaf(z, -1.9515295891e-4f, 8.3321608736e-3f), -1.6666654611e-1f);
    float sinr = fmaf(z * r, s, r);
    // cos poly
    float c = fmaf(z, fmaf(z, 2.4433157118e-5f, -1.3887316255e-3f), 4.1666645683e-2f);
    float cosr = fmaf(z, fmaf(z, c, -0.5f), 1.0f);
    float res = (q & 1) ? cosr : sinr;
    return (q & 2) ? -res : res;
}

// Exact floored fmod vs float32(2*pi), bit-matching numpy fp32 semantics.
__device__ __forceinline__ float mod_two_pi(float x) {
    const float Y = 6.2831853071795864769f;       // rounds to float32 2*pi
    float kf = floorf(__fdiv_rn(x, Y));
    float m = fmaf(-kf, Y, x);
    if (m < 0.0f)  { kf -= 1.0f; m = fmaf(-kf, Y, x); }
    if (m >= Y)    { kf += 1.0f; m = fmaf(-kf, Y, x); }
    return m;
}

// No LDS, no barriers: each thread owns one voice whose 64-sample output row
// is 256 contiguous bytes. 16 back-to-back dwordx4 stores per thread; each
// 128B line is fully written by one wave within a handful of instructions,
// so L2 write-combines to full lines (keeps round-2's 1.0x write amp) while
// waves stay completely desynced (store drain of block i overlaps compute of
// block i+k on the same CU — the overlap the barrier'd transpose kept
// destroying).
__global__ __launch_bounds__(TPB)
void fm_synth_kernel(const float* __restrict__ fm_params,
                     const float* __restrict__ f0_hz,
                     const float* __restrict__ phase_state,
                     float* __restrict__ out, int nv)
{
    int tid = threadIdx.x;
    int b   = blockIdx.x * TPB + tid;
    int bc  = min(b, nv - 1);          // clamped compute index (grid may overshoot)
    bool live = (b < nv);

    // ---- loads -----------------------------------------------------------
    const float2* fm2 = (const float2*)fm_params;   // 6 floats/voice, 8B aligned
    float2 p01 = fm2[bc * 3 + 0];
    float2 p23 = fm2[bc * 3 + 1];
    float2 p45 = fm2[bc * 3 + 2];
    float  f0  = fmaxf(f0_hz[bc], 1.0f);
    float4 st  = ((const float4*)phase_state)[bc];

    // ---- params — exact fp32 op order matching the reference -------------
    const float TWO_PI = 6.2831853071795864769f;
    float r1  = __fadd_rn(0.25f, __fmul_rn(p01.y, 15.75f));
    float fb1 = __fmul_rn(p23.x, 0.95f);
    float d2  = __fmul_rn(p23.y, 10.0f);
    float r2  = __fadd_rn(0.25f, __fmul_rn(p45.x, 15.75f));
    float fb2 = __fmul_rn(p45.y, 0.95f);
    float inc1 = __fdiv_rn(__fmul_rn(__fmul_rn(TWO_PI, f0), r1), 16000.0f);
    float inc2 = __fdiv_rn(__fmul_rn(__fmul_rn(TWO_PI, f0), r2), 16000.0f);

    float start1 = st.x, start2 = st.y;
    float l1 = st.z, l2 = st.w;

    // ---- 64-step feedback FM recurrence, samples held in registers -------
    float smp[NBLOCK];
#pragma unroll
    for (int t = 0; t < NBLOCK; ++t) {
        float tf  = (float)t;
        float ph1 = tf * inc1 + start1;
        float ph2 = tf * inc2 + start2;
        float o1 = fast_sinf(ph1 + fb1 * l1);
        float o2 = fast_sinf(ph2 + d2 * o1 + fb2 * l2);
        l1 = o1;
        l2 = o2;
        smp[t] = o2;
    }

    // ---- RMS normalize ----------------------------------------------------
    float ss = 0.0f;
#pragma unroll
    for (int t = 0; t < NBLOCK; ++t) ss = fmaf(smp[t], smp[t], ss);
    float inv = 1.0f / sqrtf(ss * 0.015625f + 1e-5f);
#pragma unroll
    for (int t = 0; t < NBLOCK; ++t) smp[t] *= inv;

    // ---- audio store: 16 dwordx4 to this thread's own 256B row ------------
    if (live) {
        float4* row = (float4*)out + (size_t)b * 16;
#pragma unroll
        for (int i = 0; i < 16; ++i) {
            float4 v4;
            v4.x = smp[4 * i + 0];
            v4.y = smp[4 * i + 1];
            v4.z = smp[4 * i + 2];
            v4.w = smp[4 * i + 3];
            row[i] = v4;
        }
    }

    // ---- phase_end (coalesced: one float4 per thread) ----------------------
    float x1 = __fadd_rn(start1, __fmul_rn(64.0f, inc1));
    float x2 = __fadd_rn(start2, __fmul_rn(64.0f, inc2));
    float4 pe;
    pe.x = mod_two_pi(x1);
    pe.y = mod_two_pi(x2);
    pe.z = l1;
    pe.w = l2;
    if (live)
        ((float4*)(out + (size_t)nv * NBLOCK))[b] = pe;
}

extern "C" void kernel_launch(void* const* d_in, const int* in_sizes, int n_in,
                              void* d_out, int out_size, void* d_ws, size_t ws_size,
                              hipStream_t stream) {
    const float* fm_params   = (const float*)d_in[0];
    const float* f0_hz       = (const float*)d_in[1];
    const float* phase_state = (const float*)d_in[2];
    float* out = (float*)d_out;
    int nv = in_sizes[1];                      // f0_hz has one element per voice
    int grid = (nv + TPB - 1) / TPB;
    fm_synth_kernel<<<grid, TPB, 0, stream>>>(fm_params, f0_hz, phase_state, out, nv);
}

// Round 5
// 169.361 us; speedup vs baseline: 1.1133x; 1.1133x over previous
//
#include <hip/hip_runtime.h>

#define NBLOCK 64
#define TPB 256
#define CHV 16              // voices per transpose chunk (one lane-group's worth)
#define LDSTR 68            // floats per voice slot: 64 + 4 pad (16B-aligned; stride 17 quads)

// sin(x) for |x| <~ 200, abs error ~1e-7.
// Cody-Waite pi/2 reduction (2 fmas) + cephes polys on [-pi/4, pi/4].
__device__ __forceinline__ float fast_sinf(float x) {
    float kf = rintf(x * 0.63661977236758134f);   // round(x * 2/pi)
    int   q  = (int)kf;
    // pi/2 = HI + LO;  HI = float(pi/2), LO = pi/2 - HI = -4.3711390e-8
    float r = fmaf(kf, -1.5707963705062866f, x);  // x - k*HI (fma-exact product)
    r = fmaf(kf, 4.3711390001862171e-8f, r);      // - k*LO
    float z = r * r;
    // sin poly
    float s = fmaf(z, fmaf(z, -1.9515295891e-4f, 8.3321608736e-3f), -1.6666654611e-1f);
    float sinr = fmaf(z * r, s, r);
    // cos poly
    float c = fmaf(z, fmaf(z, 2.4433157118e-5f, -1.3887316255e-3f), 4.1666645683e-2f);
    float cosr = fmaf(z, fmaf(z, c, -0.5f), 1.0f);
    float res = (q & 1) ? cosr : sinr;
    return (q & 2) ? -res : res;
}

// Exact floored fmod vs float32(2*pi), bit-matching numpy fp32 semantics.
__device__ __forceinline__ float mod_two_pi(float x) {
    const float Y = 6.2831853071795864769f;       // rounds to float32 2*pi
    float kf = floorf(__fdiv_rn(x, Y));
    float m = fmaf(-kf, Y, x);
    if (m < 0.0f)  { kf -= 1.0f; m = fmaf(-kf, Y, x); }
    if (m >= Y)    { kf += 1.0f; m = fmaf(-kf, Y, x); }
    return m;
}

// Barrier-free contiguous-store transpose:
//   - Each wave owns a PRIVATE 16-voice x 68-float LDS slab (4.35 KB); the
//     block total stays 17.4 KB -> 8 blocks/CU, round-0 occupancy.
//   - 4 chunks/wave: lane group g (lanes 16g..16g+15) deposits its full
//     64-sample rows (16 masked ds_write_b128; bank quad (vi+i)%8 -> 2
//     lanes/quad = free), then ALL 64 lanes read transposed (8 lanes/quad =
//     the b128 wave64 floor, round-2 pattern) and store a dense 4 KB
//     segment: 4 x 1 KB fully-contiguous wave-stores (write amp 1.0, the
//     thing round 4 proved L2 won't do for scattered 16B stores).
//   - Same-wave program order + compiler lgkmcnt covers the intra-wave WAR.
//     ZERO __syncthreads: no inter-wave coupling, so store drain of one wave
//     overlaps compute of the other 31 waves on the CU (round-2's ~40us of
//     barrier-lockstep idle is the target).
__global__ __launch_bounds__(TPB)
void fm_synth_kernel(const float* __restrict__ fm_params,
                     const float* __restrict__ f0_hz,
                     const float* __restrict__ phase_state,
                     float* __restrict__ out, int nv)
{
    __shared__ float lds[4 * CHV * LDSTR];   // 4 waves x 16 voices x 68 = 17408 B

    int tid  = threadIdx.x;
    int lane = tid & 63;
    int wv   = tid >> 6;
    int blockBase = blockIdx.x * TPB;
    int b   = blockBase + tid;
    int bc  = min(b, nv - 1);          // clamped compute index (grid may overshoot)
    bool live = (b < nv);

    // ---- loads -----------------------------------------------------------
    const float2* fm2 = (const float2*)fm_params;   // 6 floats/voice, 8B aligned
    float2 p01 = fm2[bc * 3 + 0];
    float2 p23 = fm2[bc * 3 + 1];
    float2 p45 = fm2[bc * 3 + 2];
    float  f0  = fmaxf(f0_hz[bc], 1.0f);
    float4 st  = ((const float4*)phase_state)[bc];

    // ---- params — exact fp32 op order matching the reference -------------
    const float TWO_PI = 6.2831853071795864769f;
    float r1  = __fadd_rn(0.25f, __fmul_rn(p01.y, 15.75f));
    float fb1 = __fmul_rn(p23.x, 0.95f);
    float d2  = __fmul_rn(p23.y, 10.0f);
    float r2  = __fadd_rn(0.25f, __fmul_rn(p45.x, 15.75f));
    float fb2 = __fmul_rn(p45.y, 0.95f);
    float inc1 = __fdiv_rn(__fmul_rn(__fmul_rn(TWO_PI, f0), r1), 16000.0f);
    float inc2 = __fdiv_rn(__fmul_rn(__fmul_rn(TWO_PI, f0), r2), 16000.0f);

    float start1 = st.x, start2 = st.y;
    float l1 = st.z, l2 = st.w;

    // ---- 64-step feedback FM recurrence, samples held in registers -------
    float smp[NBLOCK];
#pragma unroll
    for (int t = 0; t < NBLOCK; ++t) {
        float tf  = (float)t;
        float ph1 = tf * inc1 + start1;
        float ph2 = tf * inc2 + start2;
        float o1 = fast_sinf(ph1 + fb1 * l1);
        float o2 = fast_sinf(ph2 + d2 * o1 + fb2 * l2);
        l1 = o1;
        l2 = o2;
        smp[t] = o2;
    }

    // ---- RMS normalize ----------------------------------------------------
    float ss = 0.0f;
#pragma unroll
    for (int t = 0; t < NBLOCK; ++t) ss = fmaf(smp[t], smp[t], ss);
    float inv = 1.0f / sqrtf(ss * 0.015625f + 1e-5f);
#pragma unroll
    for (int t = 0; t < NBLOCK; ++t) smp[t] *= inv;

    // ---- phase_end first (coalesced float4/thread; drains under the
    //      transpose) -------------------------------------------------------
    float x1 = __fadd_rn(start1, __fmul_rn(64.0f, inc1));
    float x2 = __fadd_rn(start2, __fmul_rn(64.0f, inc2));
    float4 pe;
    pe.x = mod_two_pi(x1);
    pe.y = mod_two_pi(x2);
    pe.z = l1;
    pe.w = l2;
    if (live)
        ((float4*)(out + (size_t)nv * NBLOCK))[b] = pe;

    // ---- audio store: per-wave private-slab transpose, no barriers --------
    float4* out4 = (float4*)out;
    float* slab = &lds[wv * (CHV * LDSTR)];
    int lg = lane >> 4;                // which chunk this lane deposits in
    int vi = lane & 15;                // voice slot within the chunk
#pragma unroll
    for (int g = 0; g < 4; ++g) {
        if (lg == g) {                 // 16 lanes deposit their whole rows
            float* slot = &slab[vi * LDSTR];
#pragma unroll
            for (int i = 0; i < 16; ++i) {
                float4 v4;
                v4.x = smp[4 * i + 0];
                v4.y = smp[4 * i + 1];
                v4.z = smp[4 * i + 2];
                v4.w = smp[4 * i + 3];
                *(float4*)&slot[4 * i] = v4;
            }
        }
        // all 64 lanes: transposed read + dense 4 KB contiguous segment
        int vbase = blockBase + wv * 64 + g * CHV;
        size_t gb4 = (size_t)vbase * 16;       // float4 units
#pragma unroll
        for (int j = 0; j < 4; ++j) {
            int f    = j * 64 + lane;          // 0..255: flat float4 idx in segment
            int voff = f >> 4;                 // voice within chunk (0..15)
            float4 val = *(const float4*)&slab[voff * LDSTR + 4 * (f & 15)];
            if (vbase + voff < nv)
                out4[gb4 + f] = val;
        }
    }
}

extern "C" void kernel_launch(void* const* d_in, const int* in_sizes, int n_in,
                              void* d_out, int out_size, void* d_ws, size_t ws_size,
                              hipStream_t stream) {
    const float* fm_params   = (const float*)d_in[0];
    const float* f0_hz       = (const float*)d_in[1];
    const float* phase_state = (const float*)d_in[2];
    float* out = (float*)d_out;
    int nv = in_sizes[1];                      // f0_hz has one element per voice
    int grid = (nv + TPB - 1) / TPB;
    fm_synth_kernel<<<grid, TPB, 0, stream>>>(fm_params, f0_hz, phase_state, out, nv);
}